// Round 10
// baseline (8611.926 us; speedup 1.0000x reference)
//
#include <hip/hip_runtime.h>

// Problem constants
#define Tt 256

// ws layout in unsigned shorts (fp16 bit patterns / ints for flags):
//  flags : ints [0..256) arrival flags (4B packed)
//  h0 [2 parity][64 g][128 row][8]  fp16 frag-major     (g = col>>3)  [UNCHANGED]
//  h1 same
//  w0lo [32 cg][104 kg][64 n][8]  fp16, lo=(w-fp16(w))*1024   (16-h-col slices)
//  w1lo [32 cg][128 kg][64 n][8]
#define FLAGS_SHORTS 16384
#define H0OFF  16384
#define H1OFF  (H0OFF + 2*64*128*8)
#define W0LOFF (H1OFF + 2*64*128*8)
#define W1LOFF (W0LOFF + 32*104*64*8)
#define HPAR   (64*128*8)            // u16 per parity plane = 65536

typedef _Float16 h8 __attribute__((ext_vector_type(8)));
typedef float    f4 __attribute__((ext_vector_type(4)));
typedef unsigned long long ull;
typedef unsigned short u16;

#define MFMA __builtin_amdgcn_mfma_f32_16x16x32_f16
#define LOSC (1.0f/1024.0f)

__device__ inline u16 h_bits(float f){ union{_Float16 h; u16 s;} u; u.h=(_Float16)f; return u.s; }
__device__ inline float bits_f(u16 s){ union{u16 s2; _Float16 h;} u; u.s2=s; return (float)u.h; }
__device__ inline float sigm(float x){ return 1.f/(1.f+expf(-x)); }

// ---- R14 (proven): single-transaction 16B coherent load (SC0|SC1, MALL-served) ----
__device__ inline __amdgpu_buffer_rsrc_t make_rsrc(const void* base){
    return __builtin_amdgcn_make_buffer_rsrc((void*)base, /*stride*/(short)0,
                                             /*num_records*/0xFFFFFFFFu,
                                             /*flags word3*/0x00020000);
}
__device__ inline h8 ldH(__amdgpu_buffer_rsrc_t rsrc, int u16idx){
    auto d = __builtin_amdgcn_raw_buffer_load_b128(rsrc, u16idx * 2, 0, 17 /*SC0|SC1*/);
    h8 v; __builtin_memcpy(&v, &d, 16);
    return v;
}

// ---------------- pre-pack W lo-planes (fp16, x1024), [cg 32][kg][n 0..64)[8] ----------------
__global__ __launch_bounds__(256) void prepack(const float* __restrict__ W0,
                                               const float* __restrict__ W1,
                                               u16* __restrict__ ws) {
    int idx = blockIdx.x * 256 + threadIdx.x;
    const int NW0 = 32 * 104 * 64;                 // 212,992
    if (idx < NW0) {
        int cg  = idx / (104 * 64);
        int rem = idx - cg * (104 * 64);
        int kg = rem >> 6, n = rem & 63;
        int col = ((n >> 4) << 9) + (cg << 4) + (n & 15);
        u16 t[8];
#pragma unroll
        for (int j = 0; j < 8; j++) {
            int k = kg * 8 + j;
            float w = 0.f;
            if (k < 300) w = W0[k * 2048 + col];
            else if (k >= 320) w = W0[(k - 20) * 2048 + col];
            _Float16 wh = (_Float16)w;
            t[j] = h_bits((w - (float)wh) * 1024.0f);
        }
#pragma unroll
        for (int j = 0; j < 8; j++) ws[W0LOFF + (size_t)idx * 8 + j] = t[j];
    } else {
        int i2 = idx - NW0;
        if (i2 < 32 * 128 * 64) {                   // 262,144
            int cg  = i2 >> 13;                     // / (128*64)
            int rem = i2 & 8191;
            int kg = rem >> 6, n = rem & 63;
            int col = ((n >> 4) << 9) + (cg << 4) + (n & 15);
            u16 t[8];
#pragma unroll
            for (int j = 0; j < 8; j++) {
                float w = W1[(kg * 8 + j) * 2048 + col];
                _Float16 wh = (_Float16)w;
                t[j] = h_bits((w - (float)wh) * 1024.0f);
            }
#pragma unroll
            for (int j = 0; j < 8; j++) ws[W1LOFF + (size_t)i2 * 8 + j] = t[j];
        }
    }
}

// Fence-free split barrier — proven structure (threads 0..255 poll packed flags).
__device__ inline void barrier_arrive(int* __restrict__ flags, int tid, int bid, int target) {
    __builtin_amdgcn_s_waitcnt(0);
    __syncthreads();
    if (tid == 0)
        __hip_atomic_store(flags + bid, target, __ATOMIC_RELAXED, __HIP_MEMORY_SCOPE_AGENT);
}
__device__ inline void barrier_wait(int* __restrict__ flags, int tid, int target) {
    if (tid < 256)
        while (__hip_atomic_load(flags + tid, __ATOMIC_RELAXED, __HIP_MEMORY_SCOPE_AGENT) < target)
            __builtin_amdgcn_s_sleep(4);
    __syncthreads();
}

struct X8 { f4 h[4]; f4 l[4]; };

// ---------------- persistent cooperative LSTM kernel ----------------
// grid 256 x 1024 (1 block/CU, 16 waves).
// R16 (kept): per-block tile 32 rows x 16 h-cols -> coherent volume 12 MB/phase.
// R17 change (single variable): XCD-aware bid->(cg,lyr,rq) role remap. R9's FETCH
//   (3.29 GB = 12.8 MB/phase = wlo slice volume) proved the 128/104 KB wlo slices
//   thrash the 4 MB per-XCD L2 (32 blocks x ~116 KB = 3.7 MB working set). Under
//   round-robin dispatch XCD = bid&7; grouping the 8 role-sharing blocks of only
//   4 cg slices onto each XCD cuts per-XCD wlo footprint to 4x232 KB = 928 KB,
//   restoring R8's L2-resident condition at R16's halved coherent volume.
__global__ __launch_bounds__(1024, 1) void lstm_coop(
    const int* __restrict__ x, const float* __restrict__ emb,
    const float* __restrict__ W0, const float* __restrict__ b0,
    const float* __restrict__ W1, const float* __restrict__ b1,
    const float* __restrict__ Wd, const float* __restrict__ bd,
    float* __restrict__ out, u16* __restrict__ ws) {

    const int tid  = threadIdx.x;
    const int lane = tid & 63;
    const int wave = tid >> 6;        // 0..15
    const int mt   = wave & 1;        // m-tile (16 rows each; 32 rows/block)
    const int kq   = wave >> 1;       // k-eighth 0..7
    const int quad = lane >> 4;       // 0..3 : k-chunk of 8 in frags
    const int fm   = lane & 15;       // A: m, B: n, C/D: col
    const int bid  = blockIdx.x;
    // R17: XCD-aware role derivation (assumes round-robin XCD = bid&7)
    const int xcd  = bid & 7;
    const int jrole= bid >> 3;        // 0..31
    const int cg   = xcd * 4 + (jrole & 3);   // 4 cg slices per XCD
    const int lyr  = (jrole >> 2) & 1;
    const int rq   = jrole >> 3;      // 0..3 row quarter

    __shared__ u16   whi[128 * 64 * 8];   // 131,072 B (lyr0 uses first 104*64*8)
    __shared__ float csm[32][66];         //   8,448 B -> 139,520 B total

    int* flags = (int*)ws;
    const u16* w0lo = ws + W0LOFF + (size_t)cg * 104 * 64 * 8;   // block-private slice
    const u16* w1lo = ws + W1LOFF + (size_t)cg * 128 * 64 * 8;
    const __amdgpu_buffer_rsrc_t rsrc = make_rsrc(ws);

    // --- fill LDS hi-plane: layout [kg][n 0..64)[8], col = ((n>>4)<<9)+(cg<<4)+(n&15) ---
    if (lyr == 0) {
        for (int i = tid; i < 104 * 64 * 8; i += 1024) {
            int kg = i >> 9; int rem = i & 511; int n = rem >> 3; int j = rem & 7;
            int k = kg * 8 + j;
            int col = ((n >> 4) << 9) + (cg << 4) + (n & 15);
            float w = 0.f;
            if (k < 300) w = W0[k * 2048 + col];
            else if (k >= 320) w = W0[(k - 20) * 2048 + col];
            whi[i] = h_bits(w);
        }
    } else {
        for (int i = tid; i < 128 * 64 * 8; i += 1024) {
            int kg = i >> 9; int rem = i & 511; int n = rem >> 3; int j = rem & 7;
            int k = kg * 8 + j;
            int col = ((n >> 4) << 9) + (cg << 4) + (n & 15);
            whi[i] = h_bits(W1[k * 2048 + col]);
        }
    }

    // --- zero-init own h slice: rows rq*32..+32, col groups {cg*2, cg*2+1} ---
    if (tid < 256) {
        int row = rq * 32 + (tid >> 3);
        int pr  = (tid & 7) * 2;                 // h-col within 16, even
        int g = cg * 2 + (pr >> 3), c = pr & 7;
        unsigned int* pz = (unsigned int*)(ws + (lyr ? H1OFF + 1 * HPAR : H0OFF + 0 * HPAR)
                                           + g * 1024 + row * 8 + c);
        __hip_atomic_store(pz, 0u, __ATOMIC_RELAXED, __HIP_MEMORY_SCOPE_AGENT);
    }

    const int arow = rq * 32 + mt * 16 + fm;     // A-frag row (batch index)

    // bias seed for csm: thread owns cells (r0, n0) and (r0+16, n0)
    const int n0 = tid & 63, r0 = tid >> 6;
    const float* bb = lyr ? b1 : b0;
    const float sb = bb[(n0 >> 4) * 512 + (cg << 4) + (n0 & 15)];
    auto seed = [&](){ csm[r0][n0] = sb; csm[r0 + 16][n0] = sb; };

    // act cell: ONE cell per thread for tid<512: (row actm 0..31, h-col acthc 0..15)
    const int actm   = tid >> 4;
    const int acthc  = tid & 15;
    const int actrow = rq * 32 + actm;

    float cs = 0.f;

    // x-part GEMM of layer 0 for timestep pp; wave's kts: {kq, kq+8} (kt<10)
    auto xgemm = [&](int pp) -> X8 {
        X8 a;
#pragma unroll
        for (int nt = 0; nt < 4; nt++) { a.h[nt] = (f4){0,0,0,0}; a.l[nt] = (f4){0,0,0,0}; }
        int xi = x[arow * Tt + pp];
        xi = (xi < 0) ? 0 : ((xi >= 50000) ? 49999 : xi);
        const float* embrow = emb + (size_t)xi * 300;
#pragma unroll
        for (int k2 = 0; k2 < 2; k2++) {
            int kt = kq + k2 * 8;
            if (kt < 10) {
                int kbase = kt * 32 + quad * 8;
                h8 af;
                if (kt < 9) {
                    f4 u0 = *(const f4*)(embrow + kbase);
                    f4 u1 = *(const f4*)(embrow + kbase + 4);
#pragma unroll
                    for (int e = 0; e < 4; e++) { af[e] = (_Float16)u0[e]; af[4+e] = (_Float16)u1[e]; }
                } else {
#pragma unroll
                    for (int e = 0; e < 8; e++) { int kk = kbase + e; af[e] = (_Float16)((kk < 300) ? embrow[kk] : 0.f); }
                }
                int kg = kt * 4 + quad;
#pragma unroll
                for (int nt = 0; nt < 4; nt++) {
                    a.h[nt] = MFMA(af, *(const h8*)&whi[(kg * 64 + nt * 16 + fm) * 8],   a.h[nt], 0,0,0);
                    a.l[nt] = MFMA(af, *(const h8*)(w0lo + (kg * 64 + nt * 16 + fm) * 8), a.l[nt], 0,0,0);
                }
            }
        }
        return a;
    };

    X8 accx;
    seed();
    barrier_arrive(flags, tid, bid, 1);
    if (lyr == 0) accx = xgemm(0);
    barrier_wait(flags, tid, 1);

    for (int p = 0; p <= Tt; ++p) {
        const int par = p & 1, wpar = 1 - par;

        if (lyr == 1) {
            if (p >= 1) {   // ---- layer 1 for t=p-1 : g1 = [h0(p-1) | h1(p-2)] @ W1 ----
                f4 aH[4], aL[4];
#pragma unroll
                for (int nt = 0; nt < 4; nt++) { aH[nt] = (f4){0,0,0,0}; aL[nt] = (f4){0,0,0,0}; }
                // kq 0..3 -> h0 (kg 0..63); kq 4..7 -> h1 (kg 64..127)
                const int pbase = (kq >= 4 ? H1OFF : H0OFF) + par * HPAR + arow * 8;
                h8 af[4];
#pragma unroll
                for (int ktl = 0; ktl < 4; ktl++)
                    af[ktl] = ldH(rsrc, pbase + (((kq & 3) * 16 + ktl * 4 + quad) * 1024));
#pragma unroll
                for (int ktl = 0; ktl < 4; ktl++) {
                    int kg = kq * 16 + ktl * 4 + quad;
#pragma unroll
                    for (int nt = 0; nt < 4; nt++) {
                        aH[nt] = MFMA(af[ktl], *(const h8*)&whi[(kg * 64 + nt * 16 + fm) * 8],   aH[nt], 0,0,0);
                        aL[nt] = MFMA(af[ktl], *(const h8*)(w1lo + (kg * 64 + nt * 16 + fm) * 8), aL[nt], 0,0,0);
                    }
                }
#pragma unroll
                for (int nt = 0; nt < 4; nt++)
#pragma unroll
                    for (int r = 0; r < 4; r++)
                        atomicAdd(&csm[mt * 16 + quad * 4 + r][nt * 16 + fm],
                                  aH[nt][r] + aL[nt][r] * LOSC);
                __syncthreads();
                if (tid < 512) {   // gates: n = gate*16 + hc (bias pre-seeded)
                    float gi = csm[actm][acthc];
                    float gj = csm[actm][16 + acthc];
                    float gf = csm[actm][32 + acthc];
                    float go = csm[actm][48 + acthc];
                    cs = cs * sigm(gf + 1.f) + sigm(gi) * tanhf(gj);
                    float hv = tanhf(cs) * sigm(go);
                    u16 hb = h_bits(hv);
                    unsigned int pa = (unsigned int)hb | (((unsigned int)(u16)__shfl_xor((int)hb, 1, 64)) << 16);
                    if (!(acthc & 1)) {
                        int g = cg * 2 + (acthc >> 3), c = acthc & 7;
                        u16* base = ws + H1OFF + wpar * HPAR + g * 1024 + actrow * 8 + c;
                        __hip_atomic_store((unsigned int*)base, pa, __ATOMIC_RELAXED, __HIP_MEMORY_SCOPE_AGENT);
                    }
                }
                __syncthreads();
                seed();
            }
        } else {
            if (p < Tt) {   // ---- layer 0 h-part for t=p (x-part already in accx) ----
                f4 aH[4], aL[4];
#pragma unroll
                for (int nt = 0; nt < 4; nt++) { aH[nt] = accx.h[nt]; aL[nt] = accx.l[nt]; }
                const int pbase = H0OFF + par * HPAR + arow * 8;
                h8 af[2];
#pragma unroll
                for (int ktl = 0; ktl < 2; ktl++)
                    af[ktl] = ldH(rsrc, pbase + ((kq * 8 + ktl * 4 + quad) * 1024));
#pragma unroll
                for (int ktl = 0; ktl < 2; ktl++) {
                    int kg = 40 + kq * 8 + ktl * 4 + quad;
#pragma unroll
                    for (int nt = 0; nt < 4; nt++) {
                        aH[nt] = MFMA(af[ktl], *(const h8*)&whi[(kg * 64 + nt * 16 + fm) * 8],   aH[nt], 0,0,0);
                        aL[nt] = MFMA(af[ktl], *(const h8*)(w0lo + (kg * 64 + nt * 16 + fm) * 8), aL[nt], 0,0,0);
                    }
                }
#pragma unroll
                for (int nt = 0; nt < 4; nt++)
#pragma unroll
                    for (int r = 0; r < 4; r++)
                        atomicAdd(&csm[mt * 16 + quad * 4 + r][nt * 16 + fm],
                                  aH[nt][r] + aL[nt][r] * LOSC);
                __syncthreads();
                if (tid < 512) {
                    float gi = csm[actm][acthc];
                    float gj = csm[actm][16 + acthc];
                    float gf = csm[actm][32 + acthc];
                    float go = csm[actm][48 + acthc];
                    cs = cs * sigm(gf + 1.f) + sigm(gi) * tanhf(gj);
                    float hv = tanhf(cs) * sigm(go);
                    u16 hb = h_bits(hv);
                    unsigned int pa = (unsigned int)hb | (((unsigned int)(u16)__shfl_xor((int)hb, 1, 64)) << 16);
                    if (!(acthc & 1)) {
                        int g = cg * 2 + (acthc >> 3), c = acthc & 7;
                        u16* base = ws + H0OFF + wpar * HPAR + g * 1024 + actrow * 8 + c;
                        __hip_atomic_store((unsigned int*)base, pa, __ATOMIC_RELAXED, __HIP_MEMORY_SCOPE_AGENT);
                    }
                }
                __syncthreads();
                seed();
            }
        }

        barrier_arrive(flags, tid, bid, p + 2);
        if (lyr == 0 && p + 1 < Tt) accx = xgemm(p + 1);
        barrier_wait(flags, tid, p + 2);
    }

    // ---- final logits: h1(T-1) lives in parity 1 (plane layout unchanged) ----
    if (bid == 0 && tid < 256) {
        int b = tid >> 1, jj = tid & 1;
        float sum = bd[jj];
        const u16* hh = ws + H1OFF + 1 * HPAR;
        for (int g = 0; g < 64; g++) {
#pragma unroll
            for (int j4 = 0; j4 < 8; j4 += 4) {
                ull u = __hip_atomic_load((const ull*)(hh + (g * 128 + b) * 8 + j4),
                                          __ATOMIC_RELAXED, __HIP_MEMORY_SCOPE_AGENT);
#pragma unroll
                for (int e = 0; e < 4; e++)
                    sum += bits_f((u16)(u >> (16 * e))) * Wd[(g * 8 + j4 + e) * 2 + jj];
            }
        }
        out[b * 2 + jj] = sum;
    }
}

extern "C" void kernel_launch(void* const* d_in, const int* in_sizes, int n_in,
                              void* d_out, int out_size, void* d_ws, size_t ws_size,
                              hipStream_t stream) {
    const int*   x   = (const int*)d_in[0];
    const float* emb = (const float*)d_in[1];
    const float* W0  = (const float*)d_in[2];
    const float* b0  = (const float*)d_in[3];
    const float* W1  = (const float*)d_in[4];
    const float* b1  = (const float*)d_in[5];
    const float* Wd  = (const float*)d_in[6];
    const float* bd  = (const float*)d_in[7];
    float* out = (float*)d_out;
    u16* ws = (u16*)d_ws;

    hipLaunchKernelGGL(prepack, dim3(1856), dim3(256), 0, stream, W0, W1, ws);

    void* args[] = { (void*)&x, (void*)&emb, (void*)&W0, (void*)&b0, (void*)&W1,
                     (void*)&b1, (void*)&Wd, (void*)&bd, (void*)&out, (void*)&ws };
    hipLaunchCooperativeKernel((void*)lstm_coop, dim3(256), dim3(1024), args, 0, stream);
}

// Round 11
// 8590.746 us; speedup vs baseline: 1.0025x; 1.0025x over previous
//
#include <hip/hip_runtime.h>

// Problem constants
#define Tt 256

// ws layout in unsigned shorts (fp16 bit patterns / ints for flags):
//  flags : ints [0..256) arrival flags (4B packed)
//  h0 [2 parity][64 g][128 row][8]  fp16 frag-major     (g = col>>3)  [UNCHANGED]
//  h1 same
//  w0lo [32 cg][104 kg][64 n][8]  fp16, lo=(w-fp16(w))*1024   (16-h-col slices)
//  w1lo [32 cg][128 kg][64 n][8]
#define FLAGS_SHORTS 16384
#define H0OFF  16384
#define H1OFF  (H0OFF + 2*64*128*8)
#define W0LOFF (H1OFF + 2*64*128*8)
#define W1LOFF (W0LOFF + 32*104*64*8)
#define HPAR   (64*128*8)            // u16 per parity plane = 65536

typedef _Float16 h8 __attribute__((ext_vector_type(8)));
typedef float    f4 __attribute__((ext_vector_type(4)));
typedef unsigned long long ull;
typedef unsigned short u16;

#define MFMA __builtin_amdgcn_mfma_f32_16x16x32_f16
#define LOSC (1.0f/1024.0f)

__device__ inline u16 h_bits(float f){ union{_Float16 h; u16 s;} u; u.h=(_Float16)f; return u.s; }
__device__ inline float bits_f(u16 s){ union{u16 s2; _Float16 h;} u; u.s2=s; return (float)u.h; }
__device__ inline float sigm(float x){ return 1.f/(1.f+expf(-x)); }

// ---- R14 (proven): single-transaction 16B coherent load (SC0|SC1, MALL-served) ----
__device__ inline __amdgpu_buffer_rsrc_t make_rsrc(const void* base){
    return __builtin_amdgcn_make_buffer_rsrc((void*)base, /*stride*/(short)0,
                                             /*num_records*/0xFFFFFFFFu,
                                             /*flags word3*/0x00020000);
}
__device__ inline h8 ldH(__amdgpu_buffer_rsrc_t rsrc, int u16idx){
    auto d = __builtin_amdgcn_raw_buffer_load_b128(rsrc, u16idx * 2, 0, 17 /*SC0|SC1*/);
    h8 v; __builtin_memcpy(&v, &d, 16);
    return v;
}

// ---------------- pre-pack W lo-planes (fp16, x1024), [cg 32][kg][n 0..64)[8] ----------------
__global__ __launch_bounds__(256) void prepack(const float* __restrict__ W0,
                                               const float* __restrict__ W1,
                                               u16* __restrict__ ws) {
    int idx = blockIdx.x * 256 + threadIdx.x;
    const int NW0 = 32 * 104 * 64;                 // 212,992
    if (idx < NW0) {
        int cg  = idx / (104 * 64);
        int rem = idx - cg * (104 * 64);
        int kg = rem >> 6, n = rem & 63;
        int col = ((n >> 4) << 9) + (cg << 4) + (n & 15);
        u16 t[8];
#pragma unroll
        for (int j = 0; j < 8; j++) {
            int k = kg * 8 + j;
            float w = 0.f;
            if (k < 300) w = W0[k * 2048 + col];
            else if (k >= 320) w = W0[(k - 20) * 2048 + col];
            _Float16 wh = (_Float16)w;
            t[j] = h_bits((w - (float)wh) * 1024.0f);
        }
#pragma unroll
        for (int j = 0; j < 8; j++) ws[W0LOFF + (size_t)idx * 8 + j] = t[j];
    } else {
        int i2 = idx - NW0;
        if (i2 < 32 * 128 * 64) {                   // 262,144
            int cg  = i2 >> 13;                     // / (128*64)
            int rem = i2 & 8191;
            int kg = rem >> 6, n = rem & 63;
            int col = ((n >> 4) << 9) + (cg << 4) + (n & 15);
            u16 t[8];
#pragma unroll
            for (int j = 0; j < 8; j++) {
                float w = W1[(kg * 8 + j) * 2048 + col];
                _Float16 wh = (_Float16)w;
                t[j] = h_bits((w - (float)wh) * 1024.0f);
            }
#pragma unroll
            for (int j = 0; j < 8; j++) ws[W1LOFF + (size_t)i2 * 8 + j] = t[j];
        }
    }
}

// Fence-free split barrier — proven structure (threads 0..255 poll packed flags).
__device__ inline void barrier_arrive(int* __restrict__ flags, int tid, int bid, int target) {
    __builtin_amdgcn_s_waitcnt(0);
    __syncthreads();
    if (tid == 0)
        __hip_atomic_store(flags + bid, target, __ATOMIC_RELAXED, __HIP_MEMORY_SCOPE_AGENT);
}
__device__ inline void barrier_wait(int* __restrict__ flags, int tid, int target) {
    if (tid < 256)
        while (__hip_atomic_load(flags + tid, __ATOMIC_RELAXED, __HIP_MEMORY_SCOPE_AGENT) < target)
            __builtin_amdgcn_s_sleep(4);
    __syncthreads();
}

struct X8 { f4 h[4]; f4 l[4]; };

// ---------------- persistent cooperative LSTM kernel ----------------
// grid 256 x 1024 (1 block/CU, 16 waves).
// R16 (kept): per-block tile 32 rows x 16 h-cols -> coherent volume 12 MB/phase.
// R18 change (single variable vs R10): DISPATCH-AGNOSTIC role map.
//   R9/R10 FETCH data fits contiguous-chunk dispatch (XCD = bid>>5), not round-robin.
//   Role map cg=(bid>>5)*4+(bid&3), lyr=(bid>>2)&1, rq=(bid>>3)&3 is bijective and
//   keeps the per-XCD wlo working set L2-resident under BOTH mappings:
//     contiguous:  4 slices/XCD  = 928 KB
//     round-robin: 8 slices of ONE layer/XCD = 832 KB..1 MB
//   (R9 was 3.7 MB, R10 was 3.3 MB under contiguous -> L2 thrash, FETCH 3.3-3.8 GB.)
__global__ __launch_bounds__(1024, 1) void lstm_coop(
    const int* __restrict__ x, const float* __restrict__ emb,
    const float* __restrict__ W0, const float* __restrict__ b0,
    const float* __restrict__ W1, const float* __restrict__ b1,
    const float* __restrict__ Wd, const float* __restrict__ bd,
    float* __restrict__ out, u16* __restrict__ ws) {

    const int tid  = threadIdx.x;
    const int lane = tid & 63;
    const int wave = tid >> 6;        // 0..15
    const int mt   = wave & 1;        // m-tile (16 rows each; 32 rows/block)
    const int kq   = wave >> 1;       // k-eighth 0..7
    const int quad = lane >> 4;       // 0..3 : k-chunk of 8 in frags
    const int fm   = lane & 15;       // A: m, B: n, C/D: col
    const int bid  = blockIdx.x;
    // R18: dispatch-agnostic role derivation (bijective over 8 bid bits)
    const int cg   = ((bid >> 5) << 2) | (bid & 3);   // 16-h-col group 0..31
    const int lyr  = (bid >> 2) & 1;
    const int rq   = (bid >> 3) & 3;                  // row quarter 0..3

    __shared__ u16   whi[128 * 64 * 8];   // 131,072 B (lyr0 uses first 104*64*8)
    __shared__ float csm[32][66];         //   8,448 B -> 139,520 B total

    int* flags = (int*)ws;
    const u16* w0lo = ws + W0LOFF + (size_t)cg * 104 * 64 * 8;   // block-private slice
    const u16* w1lo = ws + W1LOFF + (size_t)cg * 128 * 64 * 8;
    const __amdgpu_buffer_rsrc_t rsrc = make_rsrc(ws);

    // --- fill LDS hi-plane: layout [kg][n 0..64)[8], col = ((n>>4)<<9)+(cg<<4)+(n&15) ---
    if (lyr == 0) {
        for (int i = tid; i < 104 * 64 * 8; i += 1024) {
            int kg = i >> 9; int rem = i & 511; int n = rem >> 3; int j = rem & 7;
            int k = kg * 8 + j;
            int col = ((n >> 4) << 9) + (cg << 4) + (n & 15);
            float w = 0.f;
            if (k < 300) w = W0[k * 2048 + col];
            else if (k >= 320) w = W0[(k - 20) * 2048 + col];
            whi[i] = h_bits(w);
        }
    } else {
        for (int i = tid; i < 128 * 64 * 8; i += 1024) {
            int kg = i >> 9; int rem = i & 511; int n = rem >> 3; int j = rem & 7;
            int k = kg * 8 + j;
            int col = ((n >> 4) << 9) + (cg << 4) + (n & 15);
            whi[i] = h_bits(W1[k * 2048 + col]);
        }
    }

    // --- zero-init own h slice: rows rq*32..+32, col groups {cg*2, cg*2+1} ---
    if (tid < 256) {
        int row = rq * 32 + (tid >> 3);
        int pr  = (tid & 7) * 2;                 // h-col within 16, even
        int g = cg * 2 + (pr >> 3), c = pr & 7;
        unsigned int* pz = (unsigned int*)(ws + (lyr ? H1OFF + 1 * HPAR : H0OFF + 0 * HPAR)
                                           + g * 1024 + row * 8 + c);
        __hip_atomic_store(pz, 0u, __ATOMIC_RELAXED, __HIP_MEMORY_SCOPE_AGENT);
    }

    const int arow = rq * 32 + mt * 16 + fm;     // A-frag row (batch index)

    // bias seed for csm: thread owns cells (r0, n0) and (r0+16, n0)
    const int n0 = tid & 63, r0 = tid >> 6;
    const float* bb = lyr ? b1 : b0;
    const float sb = bb[(n0 >> 4) * 512 + (cg << 4) + (n0 & 15)];
    auto seed = [&](){ csm[r0][n0] = sb; csm[r0 + 16][n0] = sb; };

    // act cell: ONE cell per thread for tid<512: (row actm 0..31, h-col acthc 0..15)
    const int actm   = tid >> 4;
    const int acthc  = tid & 15;
    const int actrow = rq * 32 + actm;

    float cs = 0.f;

    // x-part GEMM of layer 0 for timestep pp; wave's kts: {kq, kq+8} (kt<10)
    auto xgemm = [&](int pp) -> X8 {
        X8 a;
#pragma unroll
        for (int nt = 0; nt < 4; nt++) { a.h[nt] = (f4){0,0,0,0}; a.l[nt] = (f4){0,0,0,0}; }
        int xi = x[arow * Tt + pp];
        xi = (xi < 0) ? 0 : ((xi >= 50000) ? 49999 : xi);
        const float* embrow = emb + (size_t)xi * 300;
#pragma unroll
        for (int k2 = 0; k2 < 2; k2++) {
            int kt = kq + k2 * 8;
            if (kt < 10) {
                int kbase = kt * 32 + quad * 8;
                h8 af;
                if (kt < 9) {
                    f4 u0 = *(const f4*)(embrow + kbase);
                    f4 u1 = *(const f4*)(embrow + kbase + 4);
#pragma unroll
                    for (int e = 0; e < 4; e++) { af[e] = (_Float16)u0[e]; af[4+e] = (_Float16)u1[e]; }
                } else {
#pragma unroll
                    for (int e = 0; e < 8; e++) { int kk = kbase + e; af[e] = (_Float16)((kk < 300) ? embrow[kk] : 0.f); }
                }
                int kg = kt * 4 + quad;
#pragma unroll
                for (int nt = 0; nt < 4; nt++) {
                    a.h[nt] = MFMA(af, *(const h8*)&whi[(kg * 64 + nt * 16 + fm) * 8],   a.h[nt], 0,0,0);
                    a.l[nt] = MFMA(af, *(const h8*)(w0lo + (kg * 64 + nt * 16 + fm) * 8), a.l[nt], 0,0,0);
                }
            }
        }
        return a;
    };

    X8 accx;
    seed();
    barrier_arrive(flags, tid, bid, 1);
    if (lyr == 0) accx = xgemm(0);
    barrier_wait(flags, tid, 1);

    for (int p = 0; p <= Tt; ++p) {
        const int par = p & 1, wpar = 1 - par;

        if (lyr == 1) {
            if (p >= 1) {   // ---- layer 1 for t=p-1 : g1 = [h0(p-1) | h1(p-2)] @ W1 ----
                f4 aH[4], aL[4];
#pragma unroll
                for (int nt = 0; nt < 4; nt++) { aH[nt] = (f4){0,0,0,0}; aL[nt] = (f4){0,0,0,0}; }
                // kq 0..3 -> h0 (kg 0..63); kq 4..7 -> h1 (kg 64..127)
                const int pbase = (kq >= 4 ? H1OFF : H0OFF) + par * HPAR + arow * 8;
                h8 af[4];
#pragma unroll
                for (int ktl = 0; ktl < 4; ktl++)
                    af[ktl] = ldH(rsrc, pbase + (((kq & 3) * 16 + ktl * 4 + quad) * 1024));
#pragma unroll
                for (int ktl = 0; ktl < 4; ktl++) {
                    int kg = kq * 16 + ktl * 4 + quad;
#pragma unroll
                    for (int nt = 0; nt < 4; nt++) {
                        aH[nt] = MFMA(af[ktl], *(const h8*)&whi[(kg * 64 + nt * 16 + fm) * 8],   aH[nt], 0,0,0);
                        aL[nt] = MFMA(af[ktl], *(const h8*)(w1lo + (kg * 64 + nt * 16 + fm) * 8), aL[nt], 0,0,0);
                    }
                }
#pragma unroll
                for (int nt = 0; nt < 4; nt++)
#pragma unroll
                    for (int r = 0; r < 4; r++)
                        atomicAdd(&csm[mt * 16 + quad * 4 + r][nt * 16 + fm],
                                  aH[nt][r] + aL[nt][r] * LOSC);
                __syncthreads();
                if (tid < 512) {   // gates: n = gate*16 + hc (bias pre-seeded)
                    float gi = csm[actm][acthc];
                    float gj = csm[actm][16 + acthc];
                    float gf = csm[actm][32 + acthc];
                    float go = csm[actm][48 + acthc];
                    cs = cs * sigm(gf + 1.f) + sigm(gi) * tanhf(gj);
                    float hv = tanhf(cs) * sigm(go);
                    u16 hb = h_bits(hv);
                    unsigned int pa = (unsigned int)hb | (((unsigned int)(u16)__shfl_xor((int)hb, 1, 64)) << 16);
                    if (!(acthc & 1)) {
                        int g = cg * 2 + (acthc >> 3), c = acthc & 7;
                        u16* base = ws + H1OFF + wpar * HPAR + g * 1024 + actrow * 8 + c;
                        __hip_atomic_store((unsigned int*)base, pa, __ATOMIC_RELAXED, __HIP_MEMORY_SCOPE_AGENT);
                    }
                }
                __syncthreads();
                seed();
            }
        } else {
            if (p < Tt) {   // ---- layer 0 h-part for t=p (x-part already in accx) ----
                f4 aH[4], aL[4];
#pragma unroll
                for (int nt = 0; nt < 4; nt++) { aH[nt] = accx.h[nt]; aL[nt] = accx.l[nt]; }
                const int pbase = H0OFF + par * HPAR + arow * 8;
                h8 af[2];
#pragma unroll
                for (int ktl = 0; ktl < 2; ktl++)
                    af[ktl] = ldH(rsrc, pbase + ((kq * 8 + ktl * 4 + quad) * 1024));
#pragma unroll
                for (int ktl = 0; ktl < 2; ktl++) {
                    int kg = 40 + kq * 8 + ktl * 4 + quad;
#pragma unroll
                    for (int nt = 0; nt < 4; nt++) {
                        aH[nt] = MFMA(af[ktl], *(const h8*)&whi[(kg * 64 + nt * 16 + fm) * 8],   aH[nt], 0,0,0);
                        aL[nt] = MFMA(af[ktl], *(const h8*)(w0lo + (kg * 64 + nt * 16 + fm) * 8), aL[nt], 0,0,0);
                    }
                }
#pragma unroll
                for (int nt = 0; nt < 4; nt++)
#pragma unroll
                    for (int r = 0; r < 4; r++)
                        atomicAdd(&csm[mt * 16 + quad * 4 + r][nt * 16 + fm],
                                  aH[nt][r] + aL[nt][r] * LOSC);
                __syncthreads();
                if (tid < 512) {
                    float gi = csm[actm][acthc];
                    float gj = csm[actm][16 + acthc];
                    float gf = csm[actm][32 + acthc];
                    float go = csm[actm][48 + acthc];
                    cs = cs * sigm(gf + 1.f) + sigm(gi) * tanhf(gj);
                    float hv = tanhf(cs) * sigm(go);
                    u16 hb = h_bits(hv);
                    unsigned int pa = (unsigned int)hb | (((unsigned int)(u16)__shfl_xor((int)hb, 1, 64)) << 16);
                    if (!(acthc & 1)) {
                        int g = cg * 2 + (acthc >> 3), c = acthc & 7;
                        u16* base = ws + H0OFF + wpar * HPAR + g * 1024 + actrow * 8 + c;
                        __hip_atomic_store((unsigned int*)base, pa, __ATOMIC_RELAXED, __HIP_MEMORY_SCOPE_AGENT);
                    }
                }
                __syncthreads();
                seed();
            }
        }

        barrier_arrive(flags, tid, bid, p + 2);
        if (lyr == 0 && p + 1 < Tt) accx = xgemm(p + 1);
        barrier_wait(flags, tid, p + 2);
    }

    // ---- final logits: h1(T-1) lives in parity 1 (plane layout unchanged) ----
    if (bid == 0 && tid < 256) {
        int b = tid >> 1, jj = tid & 1;
        float sum = bd[jj];
        const u16* hh = ws + H1OFF + 1 * HPAR;
        for (int g = 0; g < 64; g++) {
#pragma unroll
            for (int j4 = 0; j4 < 8; j4 += 4) {
                ull u = __hip_atomic_load((const ull*)(hh + (g * 128 + b) * 8 + j4),
                                          __ATOMIC_RELAXED, __HIP_MEMORY_SCOPE_AGENT);
#pragma unroll
                for (int e = 0; e < 4; e++)
                    sum += bits_f((u16)(u >> (16 * e))) * Wd[(g * 8 + j4 + e) * 2 + jj];
            }
        }
        out[b * 2 + jj] = sum;
    }
}

extern "C" void kernel_launch(void* const* d_in, const int* in_sizes, int n_in,
                              void* d_out, int out_size, void* d_ws, size_t ws_size,
                              hipStream_t stream) {
    const int*   x   = (const int*)d_in[0];
    const float* emb = (const float*)d_in[1];
    const float* W0  = (const float*)d_in[2];
    const float* b0  = (const float*)d_in[3];
    const float* W1  = (const float*)d_in[4];
    const float* b1  = (const float*)d_in[5];
    const float* Wd  = (const float*)d_in[6];
    const float* bd  = (const float*)d_in[7];
    float* out = (float*)d_out;
    u16* ws = (u16*)d_ws;

    hipLaunchKernelGGL(prepack, dim3(1856), dim3(256), 0, stream, W0, W1, ws);

    void* args[] = { (void*)&x, (void*)&emb, (void*)&W0, (void*)&b0, (void*)&W1,
                     (void*)&b1, (void*)&Wd, (void*)&bd, (void*)&out, (void*)&ws };
    hipLaunchCooperativeKernel((void*)lstm_coop, dim3(256), dim3(1024), args, 0, stream);
}

// Round 13
// 4196.011 us; speedup vs baseline: 2.0524x; 2.0474x over previous
//
#include <hip/hip_runtime.h>

// Problem constants
#define Tt 256

// ws layout in unsigned shorts (fp16 bit patterns / ints for flags):
//  flags : ints [0..256) arrival flags (4B packed)
//  h0 [2 parity][64 g][128 row][8]  fp16 frag-major     (g = col>>3)
//  h1 same
// R19: wlo lives in LDS (computed in the fill loop); prepack deleted; ws tail unused.
#define FLAGS_SHORTS 16384
#define H0OFF  16384
#define H1OFF  (H0OFF + 2*64*128*8)
#define HPAR   (64*128*8)            // u16 per parity plane = 65536

typedef _Float16 h8 __attribute__((ext_vector_type(8)));
typedef float    f4 __attribute__((ext_vector_type(4)));
typedef unsigned long long ull;
typedef unsigned short u16;

#define MFMA __builtin_amdgcn_mfma_f32_16x16x32_f16
#define LOSC (1.0f/1024.0f)

__device__ inline u16 h_bits(float f){ union{_Float16 h; u16 s;} u; u.h=(_Float16)f; return u.s; }
__device__ inline float bits_f(u16 s){ union{u16 s2; _Float16 h;} u; u.s2=s; return (float)u.h; }
__device__ inline float sigm(float x){ return 1.f/(1.f+expf(-x)); }

// ---- R14 (proven): single-transaction 16B coherent load (SC0|SC1, MALL-served) ----
// Ordinary buffer load: vmcnt-tracked, ordered against the phase barrier by
// __syncthreads — NOT subject to the R8/R9 relaxed-atomic migration hazard.
__device__ inline __amdgpu_buffer_rsrc_t make_rsrc(const void* base){
    return __builtin_amdgcn_make_buffer_rsrc((void*)base, /*stride*/(short)0,
                                             /*num_records*/0xFFFFFFFFu,
                                             /*flags word3*/0x00020000);
}
__device__ inline h8 ldH(__amdgpu_buffer_rsrc_t rsrc, int u16idx){
    auto d = __builtin_amdgcn_raw_buffer_load_b128(rsrc, u16idx * 2, 0, 17 /*SC0|SC1*/);
    h8 v; __builtin_memcpy(&v, &d, 16);
    return v;
}

// Fence-free split barrier — proven structure (threads 0..255 poll packed flags).
// 256 blocks: thread tid polls flags[tid]. Initial poison (0xAAAAAAAA<0) needs no init.
// s_sleep(4) retained from R3 (proven passing).
__device__ inline void barrier_arrive(int* __restrict__ flags, int tid, int bid, int target) {
    __builtin_amdgcn_s_waitcnt(0);
    __syncthreads();
    if (tid == 0)
        __hip_atomic_store(flags + bid, target, __ATOMIC_RELAXED, __HIP_MEMORY_SCOPE_AGENT);
}
__device__ inline void barrier_wait(int* __restrict__ flags, int tid, int target) {
    if (tid < 256)
        while (__hip_atomic_load(flags + tid, __ATOMIC_RELAXED, __HIP_MEMORY_SCOPE_AGENT) < target)
            __builtin_amdgcn_s_sleep(4);
    __syncthreads();
}

struct X4 { f4 h0, l0, h1, l1; };

// ---------------- persistent cooperative LSTM kernel ----------------
// grid 256 x 1024 (1 block/CU, 16 waves = 4/SIMD): bid = inner*2 + lyr.
//   lyr = bid&1 : 0 -> layer-0 duties, 1 -> layer-1 duties (proven split)
//   inner = bid>>1 in [0,128): bq = inner>>6 (64-row batch half), cg = inner&63
//   (8 h-cols -> 32 gate-cols). R8-PROVEN GEOMETRY (2168 us) — R9-R11's 16-h-col
//   tile reverted (it thrashed the TCC path regardless of XCD placement).
// R19 changes vs R8 (each ingredient individually proven):
//   (1) wlo (fp16 lo-plane, x1024) lives in LDS, computed in the whi fill loop —
//       removes ~15 MB/phase of global wlo reads from L2 and the vmem queue.
//   (2) csm reduction: single bias-seeded plane + LDS atomicAdd (R9-R11 structure)
//       to fit LDS: whi 64K + wlo 64K + csm 8.4K = 139,520 B (1 block/CU).
//   (3) prepack kernel deleted (dead code once wlo is LDS-computed).
// Coherent-h protocol (16B SC0|SC1 loads, relaxed agent h-stores, flag barrier):
// byte-identical to R8.
// (R12 bench was an infrastructure failure — this is an unchanged resubmit.)
__global__ __launch_bounds__(1024, 1) void lstm_coop(
    const int* __restrict__ x, const float* __restrict__ emb,
    const float* __restrict__ W0, const float* __restrict__ b0,
    const float* __restrict__ W1, const float* __restrict__ b1,
    const float* __restrict__ Wd, const float* __restrict__ bd,
    float* __restrict__ out, u16* __restrict__ ws) {

    const int tid  = threadIdx.x;
    const int lane = tid & 63;
    const int wave = tid >> 6;        // 0..15
    const int mt   = wave & 3;        // m-tile (16 rows each)
    const int g4   = wave >> 2;       // k-quarter 0..3
    const int quad = lane >> 4;       // 0..3 : k-chunk of 8 in frags
    const int fm   = lane & 15;       // A: m, B: n, C/D: col
    const int bid  = blockIdx.x;
    const int lyr  = bid & 1;
    const int inner= bid >> 1;
    const int bq   = inner >> 6;
    const int cg   = inner & 63;

    __shared__ u16   whi[128 * 32 * 8];   // 65,536 B (lyr0 uses first 104*32*8)
    __shared__ u16   wlo[128 * 32 * 8];   // 65,536 B lo-plane
    __shared__ float csm[64 * 33];        //  8,448 B -> 139,520 B total

    int* flags = (int*)ws;
    const __amdgpu_buffer_rsrc_t rsrc = make_rsrc(ws);

    // --- fill LDS hi+lo planes of this block's layer & 32 gate columns, layout [kg][n][8] ---
    if (lyr == 0) {
        for (int i = tid; i < 104 * 32 * 8; i += 1024) {
            int kg = i >> 8; int rem = i & 255; int n = rem >> 3; int j = rem & 7;
            int k = kg * 8 + j;
            int col = ((n >> 3) << 9) + (cg << 3) + (n & 7);
            float w = 0.f;
            if (k < 300) w = W0[k * 2048 + col];
            else if (k >= 320) w = W0[(k - 20) * 2048 + col];
            _Float16 wh = (_Float16)w;
            union{_Float16 h; u16 s;} uh; uh.h = wh;
            whi[i] = uh.s;
            wlo[i] = h_bits((w - (float)wh) * 1024.0f);
        }
    } else {
        for (int i = tid; i < 128 * 32 * 8; i += 1024) {
            int kg = i >> 8; int rem = i & 255; int n = rem >> 3; int j = rem & 7;
            int k = kg * 8 + j;
            int col = ((n >> 3) << 9) + (cg << 3) + (n & 7);
            float w = W1[k * 2048 + col];
            _Float16 wh = (_Float16)w;
            union{_Float16 h; u16 s;} uh; uh.h = wh;
            whi[i] = uh.s;
            wlo[i] = h_bits((w - (float)wh) * 1024.0f);
        }
    }

    // h addressing (frag-major, unchanged): plane u16 index = cg*1024 + row*8 + c, c in [0,8)
    // --- zero-init own slice: lyr0 -> h0 parity 0 ; lyr1 -> h1 parity 1 (64 rows x 8 cols) ---
    if (tid < 256) {
        int row = bq * 64 + (tid >> 2);
        int c = (tid & 3) << 1;
        unsigned int* pz = (unsigned int*)(ws + (lyr ? H1OFF + 1 * HPAR : H0OFF + 0 * HPAR)
                                           + cg * 1024 + row * 8 + c);
        __hip_atomic_store(pz, 0u, __ATOMIC_RELAXED, __HIP_MEMORY_SCOPE_AGENT);
    }

    const int arow = bq * 64 + mt * 16 + fm;   // A-frag row (batch index)
    // act cell: ONE cell per thread for tid<512: (row actm 0..63, h-col acthc 0..7)
    const int actm   = tid >> 3;
    const int acthc  = tid & 7;
    const int actrow = bq * 64 + actm;

    // bias seed for csm (single plane, n = gate*8 + hc): 2048 cells / 1024 threads
    const int n0 = tid & 31, r0 = tid >> 5;    // n0: col 0..31, r0: row 0..31
    const float* bb = lyr ? b1 : b0;
    const float sb = bb[(n0 >> 3) * 512 + (cg << 3) + (n0 & 7)];
    auto seed = [&](){ csm[r0 * 33 + n0] = sb; csm[(r0 + 32) * 33 + n0] = sb; };

    float cs = 0.f;

    // x-part GEMM of layer 0 for timestep pp; this wave's k-quarter: kt = ktl*4 + g4 (kt<10).
    auto xgemm = [&](int pp) -> X4 {
        X4 a; a.h0 = (f4){0,0,0,0}; a.l0 = a.h0; a.h1 = a.h0; a.l1 = a.h0;
        int xi = x[arow * Tt + pp];
        xi = (xi < 0) ? 0 : ((xi >= 50000) ? 49999 : xi);
        const float* embrow = emb + (size_t)xi * 300;
#pragma unroll
        for (int ktl = 0; ktl < 3; ktl++) {
            int kt = ktl * 4 + g4;
            if (kt < 10) {
                int kbase = kt * 32 + quad * 8;
                h8 af;
                if (kt < 9) {
                    f4 u0 = *(const f4*)(embrow + kbase);
                    f4 u1 = *(const f4*)(embrow + kbase + 4);
#pragma unroll
                    for (int e = 0; e < 4; e++) { af[e] = (_Float16)u0[e]; af[4+e] = (_Float16)u1[e]; }
                } else {
#pragma unroll
                    for (int e = 0; e < 8; e++) { int kk = kbase + e; af[e] = (_Float16)((kk < 300) ? embrow[kk] : 0.f); }
                }
                int kb = (kt * 4 + quad) * 32;
                a.h0 = MFMA(af, *(const h8*)&whi[(kb + fm) * 8],      a.h0, 0,0,0);
                a.l0 = MFMA(af, *(const h8*)&wlo[(kb + fm) * 8],      a.l0, 0,0,0);
                a.h1 = MFMA(af, *(const h8*)&whi[(kb + 16 + fm) * 8], a.h1, 0,0,0);
                a.l1 = MFMA(af, *(const h8*)&wlo[(kb + 16 + fm) * 8], a.l1, 0,0,0);
            }
        }
        return a;
    };

    X4 accx;
    seed();
    barrier_arrive(flags, tid, bid, 1);
    if (lyr == 0) accx = xgemm(0);
    barrier_wait(flags, tid, 1);

    for (int p = 0; p <= Tt; ++p) {
        const int par = p & 1, wpar = 1 - par;

        if (lyr == 1) {
            if (p >= 1) {   // ---- layer 1 for t=p-1 : g1 = [h0(p-1) | h1(p-2)] @ W1 ----
                f4 aH0 = (f4){0,0,0,0}, aL0 = aH0, aH1 = aH0, aL1 = aH0;
                // k-quarters: g4 0,1 -> h0 half (kt 0..15); g4 2,3 -> h1 half (kt 16..31)
                const int hpo = (g4 >= 2 ? H1OFF : H0OFF) + par * HPAR + arow * 8;
                const int ktbase = g4 * 8;                   // global kt base
                const int ltbase = (g4 & 1) * 8;             // local kt within the h half
                h8 af[8];
#pragma unroll
                for (int ktl = 0; ktl < 8; ktl++)
                    af[ktl] = ldH(rsrc, hpo + ((ltbase + ktl) * 4 + quad) * 1024);
#pragma unroll
                for (int ktl = 0; ktl < 8; ktl++) {
                    int kb = ((ktbase + ktl) * 4 + quad) * 32;
                    aH0 = MFMA(af[ktl], *(const h8*)&whi[(kb + fm) * 8],      aH0, 0,0,0);
                    aL0 = MFMA(af[ktl], *(const h8*)&wlo[(kb + fm) * 8],      aL0, 0,0,0);
                    aH1 = MFMA(af[ktl], *(const h8*)&whi[(kb + 16 + fm) * 8], aH1, 0,0,0);
                    aL1 = MFMA(af[ktl], *(const h8*)&wlo[(kb + 16 + fm) * 8], aL1, 0,0,0);
                }
#pragma unroll
                for (int r = 0; r < 4; r++) {
                    atomicAdd(&csm[(mt * 16 + quad * 4 + r) * 33 + fm],      aH0[r] + aL0[r] * LOSC);
                    atomicAdd(&csm[(mt * 16 + quad * 4 + r) * 33 + 16 + fm], aH1[r] + aL1[r] * LOSC);
                }
                __syncthreads();
                if (tid < 512) {   // gates: col n = gate*8 + hc (bias pre-seeded)
                    float gi = csm[actm * 33 + acthc];
                    float gj = csm[actm * 33 + 8 + acthc];
                    float gf = csm[actm * 33 + 16 + acthc];
                    float go = csm[actm * 33 + 24 + acthc];
                    cs = cs * sigm(gf + 1.f) + sigm(gi) * tanhf(gj);
                    float hv = tanhf(cs) * sigm(go);
                    u16 hb = h_bits(hv);
                    unsigned int pa = (unsigned int)hb | (((unsigned int)(u16)__shfl_xor((int)hb, 1, 64)) << 16);
                    if (!(acthc & 1)) {
                        u16* base = ws + H1OFF + wpar * HPAR + cg * 1024 + actrow * 8;
                        __hip_atomic_store((unsigned int*)(base + acthc), pa, __ATOMIC_RELAXED, __HIP_MEMORY_SCOPE_AGENT);
                    }
                }
                __syncthreads();
                seed();
            }
        } else {
            if (p < Tt) {   // ---- layer 0 h-part for t=p (x-part already in accx) ----
                f4 aH0 = accx.h0, aL0 = accx.l0, aH1 = accx.h1, aL1 = accx.l1;
                const int h0o = H0OFF + par * HPAR + arow * 8;
                h8 af[4];
#pragma unroll
                for (int ktl = 0; ktl < 4; ktl++) {
                    int kt = 10 + g4 * 4 + ktl;       // kt 10..25 in quarters
                    af[ktl] = ldH(rsrc, h0o + ((kt - 10) * 4 + quad) * 1024);
                }
#pragma unroll
                for (int ktl = 0; ktl < 4; ktl++) {
                    int kt = 10 + g4 * 4 + ktl;
                    int kb = (kt * 4 + quad) * 32;
                    aH0 = MFMA(af[ktl], *(const h8*)&whi[(kb + fm) * 8],      aH0, 0,0,0);
                    aL0 = MFMA(af[ktl], *(const h8*)&wlo[(kb + fm) * 8],      aL0, 0,0,0);
                    aH1 = MFMA(af[ktl], *(const h8*)&whi[(kb + 16 + fm) * 8], aH1, 0,0,0);
                    aL1 = MFMA(af[ktl], *(const h8*)&wlo[(kb + 16 + fm) * 8], aL1, 0,0,0);
                }
#pragma unroll
                for (int r = 0; r < 4; r++) {
                    atomicAdd(&csm[(mt * 16 + quad * 4 + r) * 33 + fm],      aH0[r] + aL0[r] * LOSC);
                    atomicAdd(&csm[(mt * 16 + quad * 4 + r) * 33 + 16 + fm], aH1[r] + aL1[r] * LOSC);
                }
                __syncthreads();
                if (tid < 512) {
                    float gi = csm[actm * 33 + acthc];
                    float gj = csm[actm * 33 + 8 + acthc];
                    float gf = csm[actm * 33 + 16 + acthc];
                    float go = csm[actm * 33 + 24 + acthc];
                    cs = cs * sigm(gf + 1.f) + sigm(gi) * tanhf(gj);
                    float hv = tanhf(cs) * sigm(go);
                    u16 hb = h_bits(hv);
                    unsigned int pa = (unsigned int)hb | (((unsigned int)(u16)__shfl_xor((int)hb, 1, 64)) << 16);
                    if (!(acthc & 1)) {
                        u16* base = ws + H0OFF + wpar * HPAR + cg * 1024 + actrow * 8;
                        __hip_atomic_store((unsigned int*)(base + acthc), pa, __ATOMIC_RELAXED, __HIP_MEMORY_SCOPE_AGENT);
                    }
                }
                __syncthreads();
                seed();
            }
        }

        barrier_arrive(flags, tid, bid, p + 2);
        if (lyr == 0 && p + 1 < Tt) accx = xgemm(p + 1);
        barrier_wait(flags, tid, p + 2);
    }

    // ---- final logits: h1(T-1) lives in parity 1 (frag-major addressing, unchanged) ----
    if (bid == 0 && tid < 256) {
        int b = tid >> 1, jj = tid & 1;
        float sum = bd[jj];
        const u16* hh = ws + H1OFF + 1 * HPAR;
        for (int g = 0; g < 64; g++) {
#pragma unroll
            for (int j4 = 0; j4 < 8; j4 += 4) {
                ull u = __hip_atomic_load((const ull*)(hh + (g * 128 + b) * 8 + j4),
                                          __ATOMIC_RELAXED, __HIP_MEMORY_SCOPE_AGENT);
#pragma unroll
                for (int e = 0; e < 4; e++)
                    sum += bits_f((u16)(u >> (16 * e))) * Wd[(g * 8 + j4 + e) * 2 + jj];
            }
        }
        out[b * 2 + jj] = sum;
    }
}

extern "C" void kernel_launch(void* const* d_in, const int* in_sizes, int n_in,
                              void* d_out, int out_size, void* d_ws, size_t ws_size,
                              hipStream_t stream) {
    const int*   x   = (const int*)d_in[0];
    const float* emb = (const float*)d_in[1];
    const float* W0  = (const float*)d_in[2];
    const float* b0  = (const float*)d_in[3];
    const float* W1  = (const float*)d_in[4];
    const float* b1  = (const float*)d_in[5];
    const float* Wd  = (const float*)d_in[6];
    const float* bd  = (const float*)d_in[7];
    float* out = (float*)d_out;
    u16* ws = (u16*)d_ws;

    void* args[] = { (void*)&x, (void*)&emb, (void*)&W0, (void*)&b0, (void*)&W1,
                     (void*)&b1, (void*)&Wd, (void*)&bd, (void*)&out, (void*)&ws };
    hipLaunchCooperativeKernel((void*)lstm_coop, dim3(256), dim3(1024), args, 0, stream);
}

// Round 14
// 1664.733 us; speedup vs baseline: 5.1732x; 2.5205x over previous
//
#include <hip/hip_runtime.h>

// Problem constants
#define Tt 256

// ws layout in unsigned shorts (fp16 bit patterns / ints for flags):
//  flags : ints [0..256) arrival flags (4B packed)
//  h0 [2 parity][64 g][128 row][8]  fp16 frag-major     (g = col>>3)
//  h1 same
// R20: wlo lives in LDS (computed in the fill loop); prepack deleted; ws tail unused.
#define FLAGS_SHORTS 16384
#define H0OFF  16384
#define H1OFF  (H0OFF + 2*64*128*8)
#define HPAR   (64*128*8)            // u16 per parity plane = 65536

typedef _Float16 h8 __attribute__((ext_vector_type(8)));
typedef float    f4 __attribute__((ext_vector_type(4)));
typedef unsigned long long ull;
typedef unsigned short u16;

#define MFMA __builtin_amdgcn_mfma_f32_16x16x32_f16
#define LOSC (1.0f/1024.0f)

__device__ inline u16 h_bits(float f){ union{_Float16 h; u16 s;} u; u.h=(_Float16)f; return u.s; }
__device__ inline float bits_f(u16 s){ union{u16 s2; _Float16 h;} u; u.s2=s; return (float)u.h; }
__device__ inline float sigm(float x){ return 1.f/(1.f+expf(-x)); }

// ---- R14 (proven): single-transaction 16B coherent load (SC0|SC1, MALL-served) ----
// Ordinary buffer load: vmcnt-tracked, ordered against the phase barrier by
// __syncthreads — NOT subject to the R8/R9 relaxed-atomic migration hazard.
__device__ inline __amdgpu_buffer_rsrc_t make_rsrc(const void* base){
    return __builtin_amdgcn_make_buffer_rsrc((void*)base, /*stride*/(short)0,
                                             /*num_records*/0xFFFFFFFFu,
                                             /*flags word3*/0x00020000);
}
__device__ inline h8 ldH(__amdgpu_buffer_rsrc_t rsrc, int u16idx){
    auto d = __builtin_amdgcn_raw_buffer_load_b128(rsrc, u16idx * 2, 0, 17 /*SC0|SC1*/);
    h8 v; __builtin_memcpy(&v, &d, 16);
    return v;
}

// Fence-free split barrier — proven structure (threads 0..255 poll packed flags).
// 256 blocks: thread tid polls flags[tid]. Initial poison (0xAAAAAAAA<0) needs no init.
// s_sleep(4) retained from R3 (proven passing).
__device__ inline void barrier_arrive(int* __restrict__ flags, int tid, int bid, int target) {
    __builtin_amdgcn_s_waitcnt(0);
    __syncthreads();
    if (tid == 0)
        __hip_atomic_store(flags + bid, target, __ATOMIC_RELAXED, __HIP_MEMORY_SCOPE_AGENT);
}
__device__ inline void barrier_wait(int* __restrict__ flags, int tid, int target) {
    if (tid < 256)
        while (__hip_atomic_load(flags + tid, __ATOMIC_RELAXED, __HIP_MEMORY_SCOPE_AGENT) < target)
            __builtin_amdgcn_s_sleep(4);
    __syncthreads();
}

struct X4 { f4 h0, l0, h1, l1; };

// ---------------- persistent cooperative LSTM kernel ----------------
// grid 256 x 1024 (1 block/CU, 16 waves = 4/SIMD): bid = inner*2 + lyr.
//   lyr = bid&1 : 0 -> layer-0 duties, 1 -> layer-1 duties (proven split)
//   inner = bid>>1 in [0,128): bq = inner>>6 (64-row batch half), cg = inner&63
//   (8 h-cols -> 32 gate-cols). R8-PROVEN GEOMETRY (2168 us).
// R20 changes vs R8 (single effective variable: wlo in LDS, unconfounded):
//   (1) wlo (fp16 lo-plane, x1024) computed into LDS in the whi fill loop;
//       prepack deleted; no global wlo reads.
//   (2) csm: TWO planes, plain stores (NO atomics — R13's 8192 LDS atomicAdds/phase
//       cost +7.6 us/phase). Pass A: waves g4<2 store into plane g4. sync.
//       Pass B: waves g4>=2 do plain += into plane g4-2 (single owner per cell
//       per pass -> race-free). sync. Gate-read sums 2 planes + register biases.
//       LDS: 64K whi + 64K wlo + 16.9K csm = 147,968 B (1 block/CU).
// Coherent-h protocol (16B SC0|SC1 loads, relaxed agent h-stores, flag barrier):
// byte-identical to R8.
__global__ __launch_bounds__(1024, 1) void lstm_coop(
    const int* __restrict__ x, const float* __restrict__ emb,
    const float* __restrict__ W0, const float* __restrict__ b0,
    const float* __restrict__ W1, const float* __restrict__ b1,
    const float* __restrict__ Wd, const float* __restrict__ bd,
    float* __restrict__ out, u16* __restrict__ ws) {

    const int tid  = threadIdx.x;
    const int lane = tid & 63;
    const int wave = tid >> 6;        // 0..15
    const int mt   = wave & 3;        // m-tile (16 rows each)
    const int g4   = wave >> 2;       // k-quarter 0..3
    const int quad = lane >> 4;       // 0..3 : k-chunk of 8 in frags
    const int fm   = lane & 15;       // A: m, B: n, C/D: col
    const int bid  = blockIdx.x;
    const int lyr  = bid & 1;
    const int inner= bid >> 1;
    const int bq   = inner >> 6;
    const int cg   = inner & 63;

    __shared__ u16   whi[128 * 32 * 8];   // 65,536 B (lyr0 uses first 104*32*8)
    __shared__ u16   wlo[128 * 32 * 8];   // 65,536 B lo-plane
    __shared__ float csm[2][64 * 33];     // 16,896 B -> 147,968 B total

    int* flags = (int*)ws;
    const __amdgpu_buffer_rsrc_t rsrc = make_rsrc(ws);

    // --- fill LDS hi+lo planes of this block's layer & 32 gate columns, layout [kg][n][8] ---
    if (lyr == 0) {
        for (int i = tid; i < 104 * 32 * 8; i += 1024) {
            int kg = i >> 8; int rem = i & 255; int n = rem >> 3; int j = rem & 7;
            int k = kg * 8 + j;
            int col = ((n >> 3) << 9) + (cg << 3) + (n & 7);
            float w = 0.f;
            if (k < 300) w = W0[k * 2048 + col];
            else if (k >= 320) w = W0[(k - 20) * 2048 + col];
            _Float16 wh = (_Float16)w;
            union{_Float16 h; u16 s;} uh; uh.h = wh;
            whi[i] = uh.s;
            wlo[i] = h_bits((w - (float)wh) * 1024.0f);
        }
    } else {
        for (int i = tid; i < 128 * 32 * 8; i += 1024) {
            int kg = i >> 8; int rem = i & 255; int n = rem >> 3; int j = rem & 7;
            int k = kg * 8 + j;
            int col = ((n >> 3) << 9) + (cg << 3) + (n & 7);
            float w = W1[k * 2048 + col];
            _Float16 wh = (_Float16)w;
            union{_Float16 h; u16 s;} uh; uh.h = wh;
            whi[i] = uh.s;
            wlo[i] = h_bits((w - (float)wh) * 1024.0f);
        }
    }

    // h addressing (frag-major, unchanged): plane u16 index = cg*1024 + row*8 + c, c in [0,8)
    // --- zero-init own slice: lyr0 -> h0 parity 0 ; lyr1 -> h1 parity 1 (64 rows x 8 cols) ---
    if (tid < 256) {
        int row = bq * 64 + (tid >> 2);
        int c = (tid & 3) << 1;
        unsigned int* pz = (unsigned int*)(ws + (lyr ? H1OFF + 1 * HPAR : H0OFF + 0 * HPAR)
                                           + cg * 1024 + row * 8 + c);
        __hip_atomic_store(pz, 0u, __ATOMIC_RELAXED, __HIP_MEMORY_SCOPE_AGENT);
    }

    const int arow = bq * 64 + mt * 16 + fm;   // A-frag row (batch index)
    // act cell: ONE cell per thread for tid<512: (row actm 0..63, h-col acthc 0..7)
    const int actm   = tid >> 3;
    const int acthc  = tid & 7;
    const int actrow = bq * 64 + actm;
    const int ca = (cg << 3) + acthc;          // global h-col of the cell

    const float bi = lyr ? b1[ca]        : b0[ca];
    const float bj = lyr ? b1[512 + ca]  : b0[512 + ca];
    const float bf = lyr ? b1[1024 + ca] : b0[1024 + ca];
    const float bo = lyr ? b1[1536 + ca] : b0[1536 + ca];

    float cs = 0.f;

    // x-part GEMM of layer 0 for timestep pp; this wave's k-quarter: kt = ktl*4 + g4 (kt<10).
    auto xgemm = [&](int pp) -> X4 {
        X4 a; a.h0 = (f4){0,0,0,0}; a.l0 = a.h0; a.h1 = a.h0; a.l1 = a.h0;
        int xi = x[arow * Tt + pp];
        xi = (xi < 0) ? 0 : ((xi >= 50000) ? 49999 : xi);
        const float* embrow = emb + (size_t)xi * 300;
#pragma unroll
        for (int ktl = 0; ktl < 3; ktl++) {
            int kt = ktl * 4 + g4;
            if (kt < 10) {
                int kbase = kt * 32 + quad * 8;
                h8 af;
                if (kt < 9) {
                    f4 u0 = *(const f4*)(embrow + kbase);
                    f4 u1 = *(const f4*)(embrow + kbase + 4);
#pragma unroll
                    for (int e = 0; e < 4; e++) { af[e] = (_Float16)u0[e]; af[4+e] = (_Float16)u1[e]; }
                } else {
#pragma unroll
                    for (int e = 0; e < 8; e++) { int kk = kbase + e; af[e] = (_Float16)((kk < 300) ? embrow[kk] : 0.f); }
                }
                int kb = (kt * 4 + quad) * 32;
                a.h0 = MFMA(af, *(const h8*)&whi[(kb + fm) * 8],      a.h0, 0,0,0);
                a.l0 = MFMA(af, *(const h8*)&wlo[(kb + fm) * 8],      a.l0, 0,0,0);
                a.h1 = MFMA(af, *(const h8*)&whi[(kb + 16 + fm) * 8], a.h1, 0,0,0);
                a.l1 = MFMA(af, *(const h8*)&wlo[(kb + 16 + fm) * 8], a.l1, 0,0,0);
            }
        }
        return a;
    };

    // two-pass plain-store reduction into csm[2] (no atomics)
    auto reduce_store = [&](const f4& aH0, const f4& aL0, const f4& aH1, const f4& aL1){
        if (g4 < 2) {
#pragma unroll
            for (int r = 0; r < 4; r++) {
                csm[g4][(mt * 16 + quad * 4 + r) * 33 + fm]      = aH0[r] + aL0[r] * LOSC;
                csm[g4][(mt * 16 + quad * 4 + r) * 33 + 16 + fm] = aH1[r] + aL1[r] * LOSC;
            }
        }
        __syncthreads();
        if (g4 >= 2) {
#pragma unroll
            for (int r = 0; r < 4; r++) {
                csm[g4 - 2][(mt * 16 + quad * 4 + r) * 33 + fm]      += aH0[r] + aL0[r] * LOSC;
                csm[g4 - 2][(mt * 16 + quad * 4 + r) * 33 + 16 + fm] += aH1[r] + aL1[r] * LOSC;
            }
        }
        __syncthreads();
    };

    X4 accx;
    barrier_arrive(flags, tid, bid, 1);
    if (lyr == 0) accx = xgemm(0);
    barrier_wait(flags, tid, 1);

    for (int p = 0; p <= Tt; ++p) {
        const int par = p & 1, wpar = 1 - par;

        if (lyr == 1) {
            if (p >= 1) {   // ---- layer 1 for t=p-1 : g1 = [h0(p-1) | h1(p-2)] @ W1 ----
                f4 aH0 = (f4){0,0,0,0}, aL0 = aH0, aH1 = aH0, aL1 = aH0;
                // k-quarters: g4 0,1 -> h0 half (kt 0..15); g4 2,3 -> h1 half (kt 16..31)
                const int hpo = (g4 >= 2 ? H1OFF : H0OFF) + par * HPAR + arow * 8;
                const int ktbase = g4 * 8;                   // global kt base
                const int ltbase = (g4 & 1) * 8;             // local kt within the h half
                h8 af[8];
#pragma unroll
                for (int ktl = 0; ktl < 8; ktl++)
                    af[ktl] = ldH(rsrc, hpo + ((ltbase + ktl) * 4 + quad) * 1024);
#pragma unroll
                for (int ktl = 0; ktl < 8; ktl++) {
                    int kb = ((ktbase + ktl) * 4 + quad) * 32;
                    aH0 = MFMA(af[ktl], *(const h8*)&whi[(kb + fm) * 8],      aH0, 0,0,0);
                    aL0 = MFMA(af[ktl], *(const h8*)&wlo[(kb + fm) * 8],      aL0, 0,0,0);
                    aH1 = MFMA(af[ktl], *(const h8*)&whi[(kb + 16 + fm) * 8], aH1, 0,0,0);
                    aL1 = MFMA(af[ktl], *(const h8*)&wlo[(kb + 16 + fm) * 8], aL1, 0,0,0);
                }
                reduce_store(aH0, aL0, aH1, aL1);
                if (tid < 512) {   // gates: col n = gate*8 + hc; sum the 2 planes + reg bias
                    float gi = csm[0][actm * 33 + acthc]      + csm[1][actm * 33 + acthc]      + bi;
                    float gj = csm[0][actm * 33 + 8 + acthc]  + csm[1][actm * 33 + 8 + acthc]  + bj;
                    float gf = csm[0][actm * 33 + 16 + acthc] + csm[1][actm * 33 + 16 + acthc] + bf;
                    float go = csm[0][actm * 33 + 24 + acthc] + csm[1][actm * 33 + 24 + acthc] + bo;
                    cs = cs * sigm(gf + 1.f) + sigm(gi) * tanhf(gj);
                    float hv = tanhf(cs) * sigm(go);
                    u16 hb = h_bits(hv);
                    unsigned int pa = (unsigned int)hb | (((unsigned int)(u16)__shfl_xor((int)hb, 1, 64)) << 16);
                    if (!(acthc & 1)) {
                        u16* base = ws + H1OFF + wpar * HPAR + cg * 1024 + actrow * 8;
                        __hip_atomic_store((unsigned int*)(base + acthc), pa, __ATOMIC_RELAXED, __HIP_MEMORY_SCOPE_AGENT);
                    }
                }
            }
        } else {
            if (p < Tt) {   // ---- layer 0 h-part for t=p (x-part already in accx) ----
                f4 aH0 = accx.h0, aL0 = accx.l0, aH1 = accx.h1, aL1 = accx.l1;
                const int h0o = H0OFF + par * HPAR + arow * 8;
                h8 af[4];
#pragma unroll
                for (int ktl = 0; ktl < 4; ktl++) {
                    int kt = 10 + g4 * 4 + ktl;       // kt 10..25 in quarters
                    af[ktl] = ldH(rsrc, h0o + ((kt - 10) * 4 + quad) * 1024);
                }
#pragma unroll
                for (int ktl = 0; ktl < 4; ktl++) {
                    int kt = 10 + g4 * 4 + ktl;
                    int kb = (kt * 4 + quad) * 32;
                    aH0 = MFMA(af[ktl], *(const h8*)&whi[(kb + fm) * 8],      aH0, 0,0,0);
                    aL0 = MFMA(af[ktl], *(const h8*)&wlo[(kb + fm) * 8],      aL0, 0,0,0);
                    aH1 = MFMA(af[ktl], *(const h8*)&whi[(kb + 16 + fm) * 8], aH1, 0,0,0);
                    aL1 = MFMA(af[ktl], *(const h8*)&wlo[(kb + 16 + fm) * 8], aL1, 0,0,0);
                }
                reduce_store(aH0, aL0, aH1, aL1);
                if (tid < 512) {
                    float gi = csm[0][actm * 33 + acthc]      + csm[1][actm * 33 + acthc]      + bi;
                    float gj = csm[0][actm * 33 + 8 + acthc]  + csm[1][actm * 33 + 8 + acthc]  + bj;
                    float gf = csm[0][actm * 33 + 16 + acthc] + csm[1][actm * 33 + 16 + acthc] + bf;
                    float go = csm[0][actm * 33 + 24 + acthc] + csm[1][actm * 33 + 24 + acthc] + bo;
                    cs = cs * sigm(gf + 1.f) + sigm(gi) * tanhf(gj);
                    float hv = tanhf(cs) * sigm(go);
                    u16 hb = h_bits(hv);
                    unsigned int pa = (unsigned int)hb | (((unsigned int)(u16)__shfl_xor((int)hb, 1, 64)) << 16);
                    if (!(acthc & 1)) {
                        u16* base = ws + H0OFF + wpar * HPAR + cg * 1024 + actrow * 8;
                        __hip_atomic_store((unsigned int*)(base + acthc), pa, __ATOMIC_RELAXED, __HIP_MEMORY_SCOPE_AGENT);
                    }
                }
            }
        }

        barrier_arrive(flags, tid, bid, p + 2);
        if (lyr == 0 && p + 1 < Tt) accx = xgemm(p + 1);
        barrier_wait(flags, tid, p + 2);
    }

    // ---- final logits: h1(T-1) lives in parity 1 (frag-major addressing, unchanged) ----
    if (bid == 0 && tid < 256) {
        int b = tid >> 1, jj = tid & 1;
        float sum = bd[jj];
        const u16* hh = ws + H1OFF + 1 * HPAR;
        for (int g = 0; g < 64; g++) {
#pragma unroll
            for (int j4 = 0; j4 < 8; j4 += 4) {
                ull u = __hip_atomic_load((const ull*)(hh + (g * 128 + b) * 8 + j4),
                                          __ATOMIC_RELAXED, __HIP_MEMORY_SCOPE_AGENT);
#pragma unroll
                for (int e = 0; e < 4; e++)
                    sum += bits_f((u16)(u >> (16 * e))) * Wd[(g * 8 + j4 + e) * 2 + jj];
            }
        }
        out[b * 2 + jj] = sum;
    }
}

extern "C" void kernel_launch(void* const* d_in, const int* in_sizes, int n_in,
                              void* d_out, int out_size, void* d_ws, size_t ws_size,
                              hipStream_t stream) {
    const int*   x   = (const int*)d_in[0];
    const float* emb = (const float*)d_in[1];
    const float* W0  = (const float*)d_in[2];
    const float* b0  = (const float*)d_in[3];
    const float* W1  = (const float*)d_in[4];
    const float* b1  = (const float*)d_in[5];
    const float* Wd  = (const float*)d_in[6];
    const float* bd  = (const float*)d_in[7];
    float* out = (float*)d_out;
    u16* ws = (u16*)d_ws;

    void* args[] = { (void*)&x, (void*)&emb, (void*)&W0, (void*)&b0, (void*)&W1,
                     (void*)&b1, (void*)&Wd, (void*)&bd, (void*)&out, (void*)&ws };
    hipLaunchCooperativeKernel((void*)lstm_coop, dim3(256), dim3(1024), args, 0, stream);
}